// Round 4
// baseline (78.657 us; speedup 1.0000x reference)
//
#include <hip/hip_runtime.h>

// Dual-quaternion skinning. Round 4: 2 lanes per point (lane h owns bones
// 4h..4h+3). Per-bone math done directly in quaternion space:
//   R_ji = R(qj)R(qi)^T = R(qj ⊗ conj(qi))
// with the reference's matrix_to_quaternion sign convention (largest-|comp|
// positive) folded into the blend weight. Coalesced <=64B-stride loads,
// 1-round butterfly, x2-redundant epilogue.

__global__ void __launch_bounds__(256) dqskin_kernel(
    const float* __restrict__ sk_w,     // [N,8]
    const float* __restrict__ src_xyz,  // [N,3]
    const float* __restrict__ s_xyz,    // [N,8,3]
    const float* __restrict__ s_quat,   // [N,8,4] (w,x,y,z)
    const float* __restrict__ d_xyz,    // [N,8,3]
    const float* __restrict__ d_quat,   // [N,8,4]
    const float* __restrict__ dyn_o,    // [N]
    const float* __restrict__ src_R,    // [N,3,3]
    float* __restrict__ out,            // mu [N,3] then fr [N,3,3]
    int N)
{
    long long gid = (long long)blockIdx.x * blockDim.x + threadIdx.x;
    long long n = gid >> 1;
    int h = (int)(gid & 1);
    if (n >= N) return;

    long long b0 = n * 8 + h * 4;       // first bone this lane owns

    const float4* sq4 = reinterpret_cast<const float4*>(s_quat);
    const float4* dq4 = reinterpret_cast<const float4*>(d_quat);

    float4 wv = reinterpret_cast<const float4*>(sk_w)[n * 2 + h];
    const float wk[4] = {wv.x, wv.y, wv.z, wv.w};

    // 4 bones x 3 floats = 48B, 16B-aligned (b0*12 bytes, b0 multiple of 4)
    const float4* sx4 = reinterpret_cast<const float4*>(s_xyz + b0 * 3);
    const float4* dx4 = reinterpret_cast<const float4*>(d_xyz + b0 * 3);
    float4 sA = sx4[0], sB = sx4[1], sC = sx4[2];
    float4 dA = dx4[0], dB = dx4[1], dC = dx4[2];
    const float sx[12] = {sA.x,sA.y,sA.z,sA.w, sB.x,sB.y,sB.z,sB.w, sC.x,sC.y,sC.z,sC.w};
    const float dx[12] = {dA.x,dA.y,dA.z,dA.w, dB.x,dB.y,dB.z,dB.w, dC.x,dC.y,dC.z,dC.w};

    float acc[8] = {0.f,0.f,0.f,0.f,0.f,0.f,0.f,0.f};

    #pragma unroll
    for (int b = 0; b < 4; ++b) {
        float4 qi = sq4[b0 + b];   // (w,x,y,z)
        float4 qj = dq4[b0 + b];
        float aw=qj.x, ax=qj.y, ay=qj.z, az=qj.w;
        float bw=qi.x, bx=qi.y, by=qi.z, bz=qi.w;

        // p = qj ⊗ conj(qi)
        float pw =  aw*bw + ax*bx + ay*by + az*bz;
        float px = -aw*bx + ax*bw - ay*bz + az*by;
        float py = -aw*by + ax*bz + ay*bw - az*bx;
        float pz = -aw*bz - ax*by + ay*bx + az*bw;

        // normalize once (|p| = |qi||qj|)
        float n2  = pw*pw + px*px + py*py + pz*pz;
        float rin = rsqrtf(n2);
        pw *= rin; px *= rin; py *= rin; pz *= rin;

        // reference sign convention: largest-|comp| (first-max) positive.
        float a0 = fabsf(pw), a1 = fabsf(px), a2 = fabsf(py), a3 = fabsf(pz);
        float best = a0, sel = pw;
        if (a1 > best) { best = a1; sel = px; }
        if (a2 > best) { best = a2; sel = py; }
        if (a3 > best) { best = a3; sel = pz; }
        float ws = sel < 0.0f ? -wk[b] : wk[b];   // fold sign into weight

        // t = dst - R(p) @ src;  R(p)v = v + 2 c×(c×v + pw v), c = (px,py,pz)
        float vx = sx[b*3+0], vy = sx[b*3+1], vz = sx[b*3+2];
        float cx1 = py*vz - pz*vy + pw*vx;
        float cy1 = pz*vx - px*vz + pw*vy;
        float cz1 = px*vy - py*vx + pw*vz;
        float t0 = dx[b*3+0] - (vx + 2.0f*(py*cz1 - pz*cy1));
        float t1 = dx[b*3+1] - (vy + 2.0f*(pz*cx1 - px*cz1));
        float t2 = dx[b*3+2] - (vz + 2.0f*(px*cy1 - py*cx1));

        // qd = 0.5 * qmul([0,t], p)
        float qdw = 0.5f * (-t0*px - t1*py - t2*pz);
        float qdx = 0.5f * ( t0*pw + t1*pz - t2*py);
        float qdy = 0.5f * (-t0*pz + t1*pw + t2*px);
        float qdz = 0.5f * ( t0*py - t1*px + t2*pw);

        acc[0] += ws*pw;  acc[1] += ws*px;  acc[2] += ws*py;  acc[3] += ws*pz;
        acc[4] += ws*qdw; acc[5] += ws*qdx; acc[6] += ws*qdy; acc[7] += ws*qdz;
    }

    // ---- sum the two half-point partials (lanes 2m, 2m+1)
    #pragma unroll
    for (int i = 0; i < 8; ++i)
        acc[i] += __shfl_xor(acc[i], 1, 64);

    // ---- epilogue (x2 redundant across the pair)
    float o = dyn_o[n];
    #pragma unroll
    for (int i = 0; i < 8; ++i) acc[i] *= o;
    acc[0] += 1.0f - o;

    float nr = sqrtf(acc[0]*acc[0] + acc[1]*acc[1] + acc[2]*acc[2] + acc[3]*acc[3]);
    nr = fmaxf(nr, 1e-4f);   // DQ_EPS
    float inr = 1.0f / nr;
    float uw = acc[0]*inr, ux = acc[1]*inr, uy = acc[2]*inr, uz = acc[3]*inr;
    float vw = acc[4]*inr, vx = acc[5]*inr, vy = acc[6]*inr, vz = acc[7]*inr;
    float dp = uw*vw + ux*vx + uy*vy + uz*vz;
    vw -= dp*uw; vx -= dp*ux; vy -= dp*uy; vz -= dp*uz;

    // dq2Rt
    float Rt[9];
    {
        float s  = uw*uw + ux*ux + uy*uy + uz*uz;
        float ts = 2.0f / s;
        Rt[0]=1.0f-ts*(uy*uy+uz*uz); Rt[1]=ts*(ux*uy-uz*uw); Rt[2]=ts*(ux*uz+uy*uw);
        Rt[3]=ts*(ux*uy+uz*uw); Rt[4]=1.0f-ts*(ux*ux+uz*uz); Rt[5]=ts*(uy*uz-ux*uw);
        Rt[6]=ts*(ux*uz-uy*uw); Rt[7]=ts*(uy*uz+ux*uw); Rt[8]=1.0f-ts*(ux*ux+uy*uy);
    }
    float tx = 2.0f * (-vw*ux + vx*uw - vy*uz + vz*uy);
    float ty = 2.0f * (-vw*uy + vx*uz + vy*uw - vz*ux);
    float tz = 2.0f * (-vw*uz - vx*uy + vy*ux + vz*uw);

    // mu = Rt @ src_xyz + t
    float gx = src_xyz[n*3+0], gy = src_xyz[n*3+1], gz = src_xyz[n*3+2];
    float mu0 = Rt[0]*gx + Rt[1]*gy + Rt[2]*gz + tx;
    float mu1 = Rt[3]*gx + Rt[4]*gy + Rt[5]*gz + ty;
    float mu2 = Rt[6]*gx + Rt[7]*gy + Rt[8]*gz + tz;

    // fr = Rt @ src_R
    const float* M = src_R + n * 9;
    float m0=M[0],m1=M[1],m2=M[2],m3=M[3],m4=M[4],m5=M[5],m6=M[6],m7=M[7],m8=M[8];

    long long frb = (long long)N * 3 + n * 9;
    if (h == 0) {
        out[n*3+0] = mu0; out[n*3+1] = mu1; out[n*3+2] = mu2;
        out[frb+0] = Rt[0]*m0 + Rt[1]*m3 + Rt[2]*m6;
        out[frb+1] = Rt[0]*m1 + Rt[1]*m4 + Rt[2]*m7;
        out[frb+2] = Rt[0]*m2 + Rt[1]*m5 + Rt[2]*m8;
    } else {
        out[frb+3] = Rt[3]*m0 + Rt[4]*m3 + Rt[5]*m6;
        out[frb+4] = Rt[3]*m1 + Rt[4]*m4 + Rt[5]*m7;
        out[frb+5] = Rt[3]*m2 + Rt[4]*m5 + Rt[5]*m8;
        out[frb+6] = Rt[6]*m0 + Rt[7]*m3 + Rt[8]*m6;
        out[frb+7] = Rt[6]*m1 + Rt[7]*m4 + Rt[8]*m7;
        out[frb+8] = Rt[6]*m2 + Rt[7]*m5 + Rt[8]*m8;
    }
}

extern "C" void kernel_launch(void* const* d_in, const int* in_sizes, int n_in,
                              void* d_out, int out_size, void* d_ws, size_t ws_size,
                              hipStream_t stream) {
    const float* sk_w    = (const float*)d_in[0];
    const float* src_xyz = (const float*)d_in[1];
    const float* s_xyz   = (const float*)d_in[2];
    const float* s_quat  = (const float*)d_in[3];
    const float* d_xyz   = (const float*)d_in[4];
    const float* d_quat  = (const float*)d_in[5];
    const float* dyn_o   = (const float*)d_in[6];
    const float* src_R   = (const float*)d_in[7];
    int N = in_sizes[6];   // dyn_o is [N]
    float* out = (float*)d_out;

    long long threads = (long long)N * 2;
    int blocks = (int)((threads + 255) / 256);
    hipLaunchKernelGGL(dqskin_kernel, dim3(blocks), dim3(256), 0, stream,
                       sk_w, src_xyz, s_xyz, s_quat, d_xyz, d_quat, dyn_o, src_R, out, N);
}

// Round 5
// 51.395 us; speedup vs baseline: 1.5304x; 1.5304x over previous
//
#include <hip/hip_runtime.h>

// Dual-quaternion skinning. Round 5: 2 lanes/point math (R4) + dense
// global_load_lds quat staging (R2) + per-wave autonomous staging (no block
// barrier) + 32 KB LDS -> 5 blocks/CU. Block covers 128 points; wave w owns
// points [w*32, w*32+32) and stages only its own LDS region.

typedef const __attribute__((address_space(1))) void* gas1_t;
typedef __attribute__((address_space(3))) void* las3_t;

__global__ void __launch_bounds__(256) dqskin_kernel(
    const float* __restrict__ sk_w,     // [N,8]
    const float* __restrict__ src_xyz,  // [N,3]
    const float* __restrict__ s_xyz,    // [N,8,3]
    const float* __restrict__ s_quat,   // [N,8,4] (w,x,y,z)
    const float* __restrict__ d_xyz,    // [N,8,3]
    const float* __restrict__ d_quat,   // [N,8,4]
    const float* __restrict__ dyn_o,    // [N]
    const float* __restrict__ src_R,    // [N,3,3]
    float* __restrict__ out,            // mu [N,3] then fr [N,3,3]
    int N)
{
    __shared__ float lds_sq[4096];   // 16 KB: s_quat, 128 pts x 128 B
    __shared__ float lds_dq[4096];   // 16 KB: d_quat

    int tid  = threadIdx.x;
    int wave = tid >> 6;
    int lane = tid & 63;

    long long n0 = (long long)blockIdx.x * 128;   // first point of this block
    long long n  = n0 + (tid >> 1);               // this pair's point
    int h = tid & 1;                              // half: bones 4h..4h+3
    bool valid = n < N;
    long long nc = valid ? n : (N - 1);

    // ---- per-wave autonomous quat staging (dense exactly-once fetch).
    // Block chunk space: 1024 chunks of 16 B (128 pts x 8). Wave w owns
    // chunks [w*256, w*256+256). LDS dest linear; global chunk index is
    // XOR-involution swizzled within 64-chunk groups so the swizzled READ
    // is bank-conflict-free.
    {
        const char* gs = (const char*)s_quat;
        const char* gd = (const char*)d_quat;
        long long maxaddr = (long long)N * 128 - 16;  // tail clamp, no OOB
        long long cbase = n0 * 8;
        #pragma unroll
        for (int it = 0; it < 4; ++it) {
            int s   = wave * 256 + it * 64 + lane;    // linear slot
            int gch = s ^ ((s >> 3) & 7);             // pre-swizzled source chunk
            long long addr = (cbase + gch) * 16;
            addr = addr > maxaddr ? maxaddr : addr;
            char* dst_s = (char*)lds_sq + (size_t)(wave * 256 + it * 64) * 16;
            char* dst_d = (char*)lds_dq + (size_t)(wave * 256 + it * 64) * 16;
            __builtin_amdgcn_global_load_lds((gas1_t)(gs + addr), (las3_t)dst_s, 16, 0, 0);
            __builtin_amdgcn_global_load_lds((gas1_t)(gd + addr), (las3_t)dst_d, 16, 0, 0);
        }
    }

    // ---- per-lane register loads (issued before the drain, overlap staging)
    long long b0 = nc * 8 + h * 4;                 // first bone this lane owns
    const float4* sx4 = reinterpret_cast<const float4*>(s_xyz + b0 * 3); // 48B, 16-aligned
    const float4* dx4 = reinterpret_cast<const float4*>(d_xyz + b0 * 3);
    float4 sA = sx4[0], sB = sx4[1], sC = sx4[2];
    float4 dA = dx4[0], dB = dx4[1], dC = dx4[2];
    const float sx[12] = {sA.x,sA.y,sA.z,sA.w, sB.x,sB.y,sB.z,sB.w, sC.x,sC.y,sC.z,sC.w};
    const float dx[12] = {dA.x,dA.y,dA.z,dA.w, dB.x,dB.y,dB.z,dB.w, dC.x,dC.y,dC.z,dC.w};

    float4 wv = reinterpret_cast<const float4*>(sk_w)[nc * 2 + h];  // dense: tid*16 B
    const float wk[4] = {wv.x, wv.y, wv.z, wv.w};

    float o  = dyn_o[nc];
    float gx = src_xyz[nc*3+0], gy = src_xyz[nc*3+1], gz = src_xyz[nc*3+2];
    const float* M = src_R + nc * 9;
    float m0=M[0],m1=M[1],m2=M[2],m3=M[3],m4=M[4],m5=M[5],m6=M[6],m7=M[7],m8=M[8];

    // ---- wave-local drain (no __syncthreads: each wave reads only its region)
    asm volatile("s_waitcnt vmcnt(0)" ::: "memory");
    __builtin_amdgcn_sched_barrier(0);

    const float4* sq4 = reinterpret_cast<const float4*>(lds_sq);
    const float4* dq4 = reinterpret_cast<const float4*>(lds_dq);
    int nl = tid >> 1;                              // block-local point 0..127

    float acc[8] = {0.f,0.f,0.f,0.f,0.f,0.f,0.f,0.f};

    #pragma unroll
    for (int b = 0; b < 4; ++b) {
        int c    = nl * 8 + h * 4 + b;              // logical chunk
        int slot = c ^ ((c >> 3) & 7);              // swizzled LDS slot
        float4 qi = sq4[slot];
        float4 qj = dq4[slot];
        float aw=qj.x, ax=qj.y, ay=qj.z, az=qj.w;
        float bw=qi.x, bx=qi.y, by=qi.z, bz=qi.w;

        // p = qj ⊗ conj(qi)  (R_ji = R(p); |p| = |qi||qj|)
        float pw =  aw*bw + ax*bx + ay*by + az*bz;
        float px = -aw*bx + ax*bw - ay*bz + az*by;
        float py = -aw*by + ax*bz + ay*bw - az*bx;
        float pz = -aw*bz - ax*by + ay*bx + az*bw;

        float n2  = pw*pw + px*px + py*py + pz*pz;
        float rin = rsqrtf(n2);
        pw *= rin; px *= rin; py *= rin; pz *= rin;

        // reference sign convention: largest-|comp| (first-max) positive
        float a0 = fabsf(pw), a1 = fabsf(px), a2 = fabsf(py), a3 = fabsf(pz);
        float best = a0, sel = pw;
        if (a1 > best) { best = a1; sel = px; }
        if (a2 > best) { best = a2; sel = py; }
        if (a3 > best) { best = a3; sel = pz; }
        float ws = sel < 0.0f ? -wk[b] : wk[b];     // fold sign into weight

        // t = dst - R(p) @ src;  R(p)v = v + 2 c×(c×v + pw v)
        float vx = sx[b*3+0], vy = sx[b*3+1], vz = sx[b*3+2];
        float cx1 = py*vz - pz*vy + pw*vx;
        float cy1 = pz*vx - px*vz + pw*vy;
        float cz1 = px*vy - py*vx + pw*vz;
        float t0 = dx[b*3+0] - (vx + 2.0f*(py*cz1 - pz*cy1));
        float t1 = dx[b*3+1] - (vy + 2.0f*(pz*cx1 - px*cz1));
        float t2 = dx[b*3+2] - (vz + 2.0f*(px*cy1 - py*cx1));

        // qd = 0.5 * qmul([0,t], p)
        float qdw = 0.5f * (-t0*px - t1*py - t2*pz);
        float qdx = 0.5f * ( t0*pw + t1*pz - t2*py);
        float qdy = 0.5f * (-t0*pz + t1*pw + t2*px);
        float qdz = 0.5f * ( t0*py - t1*px + t2*pw);

        acc[0] += ws*pw;  acc[1] += ws*px;  acc[2] += ws*py;  acc[3] += ws*pz;
        acc[4] += ws*qdw; acc[5] += ws*qdx; acc[6] += ws*qdy; acc[7] += ws*qdz;
    }

    // ---- sum the two half-point partials (lane pair 2m, 2m+1)
    #pragma unroll
    for (int i = 0; i < 8; ++i)
        acc[i] += __shfl_xor(acc[i], 1, 64);

    // ---- epilogue (x2 redundant across the pair)
    #pragma unroll
    for (int i = 0; i < 8; ++i) acc[i] *= o;
    acc[0] += 1.0f - o;

    float nr = sqrtf(acc[0]*acc[0] + acc[1]*acc[1] + acc[2]*acc[2] + acc[3]*acc[3]);
    nr = fmaxf(nr, 1e-4f);   // DQ_EPS
    float inr = 1.0f / nr;
    float uw = acc[0]*inr, ux = acc[1]*inr, uy = acc[2]*inr, uz = acc[3]*inr;
    float vw = acc[4]*inr, vx = acc[5]*inr, vy = acc[6]*inr, vz = acc[7]*inr;
    float dp = uw*vw + ux*vx + uy*vy + uz*vz;
    vw -= dp*uw; vx -= dp*ux; vy -= dp*uy; vz -= dp*uz;

    // dq2Rt
    float Rt[9];
    {
        float s  = uw*uw + ux*ux + uy*uy + uz*uz;
        float ts = 2.0f / s;
        Rt[0]=1.0f-ts*(uy*uy+uz*uz); Rt[1]=ts*(ux*uy-uz*uw); Rt[2]=ts*(ux*uz+uy*uw);
        Rt[3]=ts*(ux*uy+uz*uw); Rt[4]=1.0f-ts*(ux*ux+uz*uz); Rt[5]=ts*(uy*uz-ux*uw);
        Rt[6]=ts*(ux*uz-uy*uw); Rt[7]=ts*(uy*uz+ux*uw); Rt[8]=1.0f-ts*(ux*ux+uy*uy);
    }
    float tx = 2.0f * (-vw*ux + vx*uw - vy*uz + vz*uy);
    float ty = 2.0f * (-vw*uy + vx*uz + vy*uw - vz*ux);
    float tz = 2.0f * (-vw*uz - vx*uy + vy*ux + vz*uw);

    float mu0 = Rt[0]*gx + Rt[1]*gy + Rt[2]*gz + tx;
    float mu1 = Rt[3]*gx + Rt[4]*gy + Rt[5]*gz + ty;
    float mu2 = Rt[6]*gx + Rt[7]*gy + Rt[8]*gz + tz;

    long long frb = (long long)N * 3 + n * 9;
    if (valid) {
        if (h == 0) {
            out[n*3+0] = mu0; out[n*3+1] = mu1; out[n*3+2] = mu2;
            out[frb+0] = Rt[0]*m0 + Rt[1]*m3 + Rt[2]*m6;
            out[frb+1] = Rt[0]*m1 + Rt[1]*m4 + Rt[2]*m7;
            out[frb+2] = Rt[0]*m2 + Rt[1]*m5 + Rt[2]*m8;
        } else {
            out[frb+3] = Rt[3]*m0 + Rt[4]*m3 + Rt[5]*m6;
            out[frb+4] = Rt[3]*m1 + Rt[4]*m4 + Rt[5]*m7;
            out[frb+5] = Rt[3]*m2 + Rt[4]*m5 + Rt[5]*m8;
            out[frb+6] = Rt[6]*m0 + Rt[7]*m3 + Rt[8]*m6;
            out[frb+7] = Rt[6]*m1 + Rt[7]*m4 + Rt[8]*m7;
            out[frb+8] = Rt[6]*m2 + Rt[7]*m5 + Rt[8]*m8;
        }
    }
}

extern "C" void kernel_launch(void* const* d_in, const int* in_sizes, int n_in,
                              void* d_out, int out_size, void* d_ws, size_t ws_size,
                              hipStream_t stream) {
    const float* sk_w    = (const float*)d_in[0];
    const float* src_xyz = (const float*)d_in[1];
    const float* s_xyz   = (const float*)d_in[2];
    const float* s_quat  = (const float*)d_in[3];
    const float* d_xyz   = (const float*)d_in[4];
    const float* d_quat  = (const float*)d_in[5];
    const float* dyn_o   = (const float*)d_in[6];
    const float* src_R   = (const float*)d_in[7];
    int N = in_sizes[6];   // dyn_o is [N]
    float* out = (float*)d_out;

    int blocks = (N + 127) / 128;   // 128 points per 256-thread block
    hipLaunchKernelGGL(dqskin_kernel, dim3(blocks), dim3(256), 0, stream,
                       sk_w, src_xyz, s_xyz, s_quat, d_xyz, d_quat, dyn_o, src_R, out, N);
}

// Round 6
// 50.875 us; speedup vs baseline: 1.5461x; 1.0102x over previous
//
#include <hip/hip_runtime.h>

// Dual-quaternion skinning. Round 6: 2 lanes/point, NO LDS. All 15 float4
// loads per lane issued as one tight burst (sched_barrier-pinned) so the
// 64B-strided quat lines' 4 touches are concurrently in flight and merge in
// L2/MSHR instead of refetching. Cheap quaternion-composition math (R4),
// 1-round butterfly, x2 epilogue.

__global__ void __launch_bounds__(256) dqskin_kernel(
    const float* __restrict__ sk_w,     // [N,8]
    const float* __restrict__ src_xyz,  // [N,3]
    const float* __restrict__ s_xyz,    // [N,8,3]
    const float* __restrict__ s_quat,   // [N,8,4] (w,x,y,z)
    const float* __restrict__ d_xyz,    // [N,8,3]
    const float* __restrict__ d_quat,   // [N,8,4]
    const float* __restrict__ dyn_o,    // [N]
    const float* __restrict__ src_R,    // [N,3,3]
    float* __restrict__ out,            // mu [N,3] then fr [N,3,3]
    int N)
{
    long long gid = (long long)blockIdx.x * blockDim.x + threadIdx.x;
    long long n = gid >> 1;
    int h = (int)(gid & 1);
    bool valid = n < N;
    long long nc = valid ? n : (N - 1);

    long long b0 = nc * 8 + h * 4;       // first bone this lane owns

    // ================= load burst (all VMEM issued before any math) =========
    const float4* sq4 = reinterpret_cast<const float4*>(s_quat);
    const float4* dq4 = reinterpret_cast<const float4*>(d_quat);
    float4 qi0 = sq4[b0+0], qi1 = sq4[b0+1], qi2 = sq4[b0+2], qi3 = sq4[b0+3];
    float4 qj0 = dq4[b0+0], qj1 = dq4[b0+1], qj2 = dq4[b0+2], qj3 = dq4[b0+3];

    const float4* sx4 = reinterpret_cast<const float4*>(s_xyz + b0 * 3); // 48B aligned
    const float4* dx4 = reinterpret_cast<const float4*>(d_xyz + b0 * 3);
    float4 sA = sx4[0], sB = sx4[1], sC = sx4[2];
    float4 dA = dx4[0], dB = dx4[1], dC = dx4[2];

    float4 wv = reinterpret_cast<const float4*>(sk_w)[nc * 2 + h];
    float o  = dyn_o[nc];
    float gx = src_xyz[nc*3+0], gy = src_xyz[nc*3+1], gz = src_xyz[nc*3+2];
    const float* M = src_R + nc * 9;
    float m0=M[0],m1=M[1],m2=M[2],m3=M[3],m4=M[4],m5=M[5],m6=M[6],m7=M[7],m8=M[8];
    __builtin_amdgcn_sched_barrier(0);   // pin: no math scheduled above loads
    // ========================================================================

    const float sx[12] = {sA.x,sA.y,sA.z,sA.w, sB.x,sB.y,sB.z,sB.w, sC.x,sC.y,sC.z,sC.w};
    const float dx[12] = {dA.x,dA.y,dA.z,dA.w, dB.x,dB.y,dB.z,dB.w, dC.x,dC.y,dC.z,dC.w};
    const float wk[4] = {wv.x, wv.y, wv.z, wv.w};
    const float4 qis[4] = {qi0, qi1, qi2, qi3};
    const float4 qjs[4] = {qj0, qj1, qj2, qj3};

    float acc[8] = {0.f,0.f,0.f,0.f,0.f,0.f,0.f,0.f};

    #pragma unroll
    for (int b = 0; b < 4; ++b) {
        float4 qi = qis[b], qj = qjs[b];
        float aw=qj.x, ax=qj.y, ay=qj.z, az=qj.w;
        float bw=qi.x, bx=qi.y, by=qi.z, bz=qi.w;

        // p = qj ⊗ conj(qi);  R_ji = R(p);  |p| = |qi||qj|
        float pw =  aw*bw + ax*bx + ay*by + az*bz;
        float px = -aw*bx + ax*bw - ay*bz + az*by;
        float py = -aw*by + ax*bz + ay*bw - az*bx;
        float pz = -aw*bz - ax*by + ay*bx + az*bw;

        float n2  = pw*pw + px*px + py*py + pz*pz;
        float rin = rsqrtf(n2);
        pw *= rin; px *= rin; py *= rin; pz *= rin;

        // reference sign convention: largest-|comp| (first-max) positive
        float a0 = fabsf(pw), a1 = fabsf(px), a2 = fabsf(py), a3 = fabsf(pz);
        float best = a0, sel = pw;
        if (a1 > best) { best = a1; sel = px; }
        if (a2 > best) { best = a2; sel = py; }
        if (a3 > best) { best = a3; sel = pz; }
        float ws = sel < 0.0f ? -wk[b] : wk[b];   // fold sign into weight

        // t = dst - R(p) @ src;  R(p)v = v + 2 c×(c×v + pw v)
        float vx = sx[b*3+0], vy = sx[b*3+1], vz = sx[b*3+2];
        float cx1 = py*vz - pz*vy + pw*vx;
        float cy1 = pz*vx - px*vz + pw*vy;
        float cz1 = px*vy - py*vx + pw*vz;
        float t0 = dx[b*3+0] - (vx + 2.0f*(py*cz1 - pz*cy1));
        float t1 = dx[b*3+1] - (vy + 2.0f*(pz*cx1 - px*cz1));
        float t2 = dx[b*3+2] - (vz + 2.0f*(px*cy1 - py*cx1));

        // qd = 0.5 * qmul([0,t], p)
        float qdw = 0.5f * (-t0*px - t1*py - t2*pz);
        float qdx = 0.5f * ( t0*pw + t1*pz - t2*py);
        float qdy = 0.5f * (-t0*pz + t1*pw + t2*px);
        float qdz = 0.5f * ( t0*py - t1*px + t2*pw);

        acc[0] += ws*pw;  acc[1] += ws*px;  acc[2] += ws*py;  acc[3] += ws*pz;
        acc[4] += ws*qdw; acc[5] += ws*qdx; acc[6] += ws*qdy; acc[7] += ws*qdz;
    }

    // ---- sum the two half-point partials (lane pair 2m, 2m+1)
    #pragma unroll
    for (int i = 0; i < 8; ++i)
        acc[i] += __shfl_xor(acc[i], 1, 64);

    // ---- epilogue (x2 redundant across the pair)
    #pragma unroll
    for (int i = 0; i < 8; ++i) acc[i] *= o;
    acc[0] += 1.0f - o;

    float nr = sqrtf(acc[0]*acc[0] + acc[1]*acc[1] + acc[2]*acc[2] + acc[3]*acc[3]);
    nr = fmaxf(nr, 1e-4f);   // DQ_EPS
    float inr = 1.0f / nr;
    float uw = acc[0]*inr, ux = acc[1]*inr, uy = acc[2]*inr, uz = acc[3]*inr;
    float vw = acc[4]*inr, vx = acc[5]*inr, vy = acc[6]*inr, vz = acc[7]*inr;
    float dp = uw*vw + ux*vx + uy*vy + uz*vz;
    vw -= dp*uw; vx -= dp*ux; vy -= dp*uy; vz -= dp*uz;

    // dq2Rt
    float Rt[9];
    {
        float s  = uw*uw + ux*ux + uy*uy + uz*uz;
        float ts = 2.0f / s;
        Rt[0]=1.0f-ts*(uy*uy+uz*uz); Rt[1]=ts*(ux*uy-uz*uw); Rt[2]=ts*(ux*uz+uy*uw);
        Rt[3]=ts*(ux*uy+uz*uw); Rt[4]=1.0f-ts*(ux*ux+uz*uz); Rt[5]=ts*(uy*uz-ux*uw);
        Rt[6]=ts*(ux*uz-uy*uw); Rt[7]=ts*(uy*uz+ux*uw); Rt[8]=1.0f-ts*(ux*ux+uy*uy);
    }
    float tx = 2.0f * (-vw*ux + vx*uw - vy*uz + vz*uy);
    float ty = 2.0f * (-vw*uy + vx*uz + vy*uw - vz*ux);
    float tz = 2.0f * (-vw*uz - vx*uy + vy*ux + vz*uw);

    float mu0 = Rt[0]*gx + Rt[1]*gy + Rt[2]*gz + tx;
    float mu1 = Rt[3]*gx + Rt[4]*gy + Rt[5]*gz + ty;
    float mu2 = Rt[6]*gx + Rt[7]*gy + Rt[8]*gz + tz;

    long long frb = (long long)N * 3 + n * 9;
    if (valid) {
        if (h == 0) {
            out[n*3+0] = mu0; out[n*3+1] = mu1; out[n*3+2] = mu2;
            out[frb+0] = Rt[0]*m0 + Rt[1]*m3 + Rt[2]*m6;
            out[frb+1] = Rt[0]*m1 + Rt[1]*m4 + Rt[2]*m7;
            out[frb+2] = Rt[0]*m2 + Rt[1]*m5 + Rt[2]*m8;
        } else {
            out[frb+3] = Rt[3]*m0 + Rt[4]*m3 + Rt[5]*m6;
            out[frb+4] = Rt[3]*m1 + Rt[4]*m4 + Rt[5]*m7;
            out[frb+5] = Rt[3]*m2 + Rt[4]*m5 + Rt[5]*m8;
            out[frb+6] = Rt[6]*m0 + Rt[7]*m3 + Rt[8]*m6;
            out[frb+7] = Rt[6]*m1 + Rt[7]*m4 + Rt[8]*m7;
            out[frb+8] = Rt[6]*m2 + Rt[7]*m5 + Rt[8]*m8;
        }
    }
}

extern "C" void kernel_launch(void* const* d_in, const int* in_sizes, int n_in,
                              void* d_out, int out_size, void* d_ws, size_t ws_size,
                              hipStream_t stream) {
    const float* sk_w    = (const float*)d_in[0];
    const float* src_xyz = (const float*)d_in[1];
    const float* s_xyz   = (const float*)d_in[2];
    const float* s_quat  = (const float*)d_in[3];
    const float* d_xyz   = (const float*)d_in[4];
    const float* d_quat  = (const float*)d_in[5];
    const float* dyn_o   = (const float*)d_in[6];
    const float* src_R   = (const float*)d_in[7];
    int N = in_sizes[6];   // dyn_o is [N]
    float* out = (float*)d_out;

    long long threads = (long long)N * 2;
    int blocks = (int)((threads + 255) / 256);
    hipLaunchKernelGGL(dqskin_kernel, dim3(blocks), dim3(256), 0, stream,
                       sk_w, src_xyz, s_xyz, s_quat, d_xyz, d_quat, dyn_o, src_R, out, N);
}

// Round 7
// 50.195 us; speedup vs baseline: 1.5670x; 1.0135x over previous
//
#include <hip/hip_runtime.h>

// Dual-quaternion skinning. Round 7: R6 structure (2 lanes/point, no LDS,
// burst loads) x 2 points per thread (n and n+N/2). Both points' loads are
// issued in one burst before any math; math/stores of point 1 overlap the
// in-flight loads of point 2 (compiler emits counted vmcnt waits). Doubles
// per-wave memory-level parallelism to attack the latency bound.

__global__ void __launch_bounds__(256) dqskin_kernel(
    const float* __restrict__ sk_w,     // [N,8]
    const float* __restrict__ src_xyz,  // [N,3]
    const float* __restrict__ s_xyz,    // [N,8,3]
    const float* __restrict__ s_quat,   // [N,8,4] (w,x,y,z)
    const float* __restrict__ d_xyz,    // [N,8,3]
    const float* __restrict__ d_quat,   // [N,8,4]
    const float* __restrict__ dyn_o,    // [N]
    const float* __restrict__ src_R,    // [N,3,3]
    float* __restrict__ out,            // mu [N,3] then fr [N,3,3]
    int N)
{
    long long half = ((long long)N + 1) >> 1;
    long long gid = (long long)blockIdx.x * blockDim.x + threadIdx.x;
    long long pr = gid >> 1;            // pair-row in [0, half)
    int h = (int)(gid & 1);
    if (pr >= half) return;

    long long n1 = pr;                  // always < N
    long long n2 = pr + half;
    bool v2 = n2 < N;
    long long nc2 = v2 ? n2 : (N - 1);

    const float4* sq4 = reinterpret_cast<const float4*>(s_quat);
    const float4* dq4 = reinterpret_cast<const float4*>(d_quat);
    const float4* w4  = reinterpret_cast<const float4*>(sk_w);

    long long bA = n1 * 8 + h * 4;      // first bone, point 1
    long long bB = nc2 * 8 + h * 4;     // first bone, point 2

    // ================= load burst: BOTH points, before any math =============
    float4 qiA0 = sq4[bA+0], qiA1 = sq4[bA+1], qiA2 = sq4[bA+2], qiA3 = sq4[bA+3];
    float4 qjA0 = dq4[bA+0], qjA1 = dq4[bA+1], qjA2 = dq4[bA+2], qjA3 = dq4[bA+3];
    const float4* sxA = reinterpret_cast<const float4*>(s_xyz + bA * 3);
    const float4* dxA = reinterpret_cast<const float4*>(d_xyz + bA * 3);
    float4 sA0 = sxA[0], sA1 = sxA[1], sA2 = sxA[2];
    float4 dA0 = dxA[0], dA1 = dxA[1], dA2 = dxA[2];
    float4 wvA = w4[n1 * 2 + h];
    float oA  = dyn_o[n1];
    float gAx = src_xyz[n1*3+0], gAy = src_xyz[n1*3+1], gAz = src_xyz[n1*3+2];
    const float* MA = src_R + n1 * 9;
    float mA0=MA[0],mA1=MA[1],mA2=MA[2],mA3=MA[3],mA4=MA[4],mA5=MA[5],mA6=MA[6],mA7=MA[7],mA8=MA[8];

    float4 qiB0 = sq4[bB+0], qiB1 = sq4[bB+1], qiB2 = sq4[bB+2], qiB3 = sq4[bB+3];
    float4 qjB0 = dq4[bB+0], qjB1 = dq4[bB+1], qjB2 = dq4[bB+2], qjB3 = dq4[bB+3];
    const float4* sxB = reinterpret_cast<const float4*>(s_xyz + bB * 3);
    const float4* dxB = reinterpret_cast<const float4*>(d_xyz + bB * 3);
    float4 sB0 = sxB[0], sB1 = sxB[1], sB2 = sxB[2];
    float4 dB0 = dxB[0], dB1 = dxB[1], dB2 = dxB[2];
    float4 wvB = w4[nc2 * 2 + h];
    float oB  = dyn_o[nc2];
    float gBx = src_xyz[nc2*3+0], gBy = src_xyz[nc2*3+1], gBz = src_xyz[nc2*3+2];
    const float* MB = src_R + nc2 * 9;
    float mB0=MB[0],mB1=MB[1],mB2=MB[2],mB3=MB[3],mB4=MB[4],mB5=MB[5],mB6=MB[6],mB7=MB[7],mB8=MB[8];
    __builtin_amdgcn_sched_barrier(0);   // pin: all loads issued above
    // ========================================================================

    #define POINT_BODY(qi0_,qi1_,qi2_,qi3_, qj0_,qj1_,qj2_,qj3_, s0_,s1_,s2_, d0_,d1_,d2_, \
                       wv_, o_, gx_,gy_,gz_, m0_,m1_,m2_,m3_,m4_,m5_,m6_,m7_,m8_, n_, doit_) \
    do { \
        const float4 qis[4] = {qi0_, qi1_, qi2_, qi3_}; \
        const float4 qjs[4] = {qj0_, qj1_, qj2_, qj3_}; \
        const float sx[12] = {s0_.x,s0_.y,s0_.z,s0_.w, s1_.x,s1_.y,s1_.z,s1_.w, s2_.x,s2_.y,s2_.z,s2_.w}; \
        const float dx[12] = {d0_.x,d0_.y,d0_.z,d0_.w, d1_.x,d1_.y,d1_.z,d1_.w, d2_.x,d2_.y,d2_.z,d2_.w}; \
        const float wk[4] = {wv_.x, wv_.y, wv_.z, wv_.w}; \
        float acc[8] = {0.f,0.f,0.f,0.f,0.f,0.f,0.f,0.f}; \
        _Pragma("unroll") \
        for (int b = 0; b < 4; ++b) { \
            float4 qi = qis[b], qj = qjs[b]; \
            float aw=qj.x, ax=qj.y, ay=qj.z, az=qj.w; \
            float bw=qi.x, bx=qi.y, by=qi.z, bz=qi.w; \
            float pw =  aw*bw + ax*bx + ay*by + az*bz; \
            float px = -aw*bx + ax*bw - ay*bz + az*by; \
            float py = -aw*by + ax*bz + ay*bw - az*bx; \
            float pz = -aw*bz - ax*by + ay*bx + az*bw; \
            float n2v = pw*pw + px*px + py*py + pz*pz; \
            float rin = rsqrtf(n2v); \
            pw *= rin; px *= rin; py *= rin; pz *= rin; \
            float a0 = fabsf(pw), a1 = fabsf(px), a2 = fabsf(py), a3 = fabsf(pz); \
            float best = a0, sel = pw; \
            if (a1 > best) { best = a1; sel = px; } \
            if (a2 > best) { best = a2; sel = py; } \
            if (a3 > best) { best = a3; sel = pz; } \
            float ws = sel < 0.0f ? -wk[b] : wk[b]; \
            float vx = sx[b*3+0], vy = sx[b*3+1], vz = sx[b*3+2]; \
            float cx1 = py*vz - pz*vy + pw*vx; \
            float cy1 = pz*vx - px*vz + pw*vy; \
            float cz1 = px*vy - py*vx + pw*vz; \
            float t0 = dx[b*3+0] - (vx + 2.0f*(py*cz1 - pz*cy1)); \
            float t1 = dx[b*3+1] - (vy + 2.0f*(pz*cx1 - px*cz1)); \
            float t2 = dx[b*3+2] - (vz + 2.0f*(px*cy1 - py*cx1)); \
            float qdw = 0.5f * (-t0*px - t1*py - t2*pz); \
            float qdx = 0.5f * ( t0*pw + t1*pz - t2*py); \
            float qdy = 0.5f * (-t0*pz + t1*pw + t2*px); \
            float qdz = 0.5f * ( t0*py - t1*px + t2*pw); \
            acc[0] += ws*pw;  acc[1] += ws*px;  acc[2] += ws*py;  acc[3] += ws*pz; \
            acc[4] += ws*qdw; acc[5] += ws*qdx; acc[6] += ws*qdy; acc[7] += ws*qdz; \
        } \
        _Pragma("unroll") \
        for (int i = 0; i < 8; ++i) \
            acc[i] += __shfl_xor(acc[i], 1, 64); \
        _Pragma("unroll") \
        for (int i = 0; i < 8; ++i) acc[i] *= o_; \
        acc[0] += 1.0f - o_; \
        float nr = sqrtf(acc[0]*acc[0] + acc[1]*acc[1] + acc[2]*acc[2] + acc[3]*acc[3]); \
        nr = fmaxf(nr, 1e-4f); \
        float inr = 1.0f / nr; \
        float uw = acc[0]*inr, ux = acc[1]*inr, uy = acc[2]*inr, uz = acc[3]*inr; \
        float vw = acc[4]*inr, vxx = acc[5]*inr, vyy = acc[6]*inr, vzz = acc[7]*inr; \
        float dp = uw*vw + ux*vxx + uy*vyy + uz*vzz; \
        vw -= dp*uw; vxx -= dp*ux; vyy -= dp*uy; vzz -= dp*uz; \
        float Rt[9]; \
        { \
            float s2v = uw*uw + ux*ux + uy*uy + uz*uz; \
            float ts = 2.0f / s2v; \
            Rt[0]=1.0f-ts*(uy*uy+uz*uz); Rt[1]=ts*(ux*uy-uz*uw); Rt[2]=ts*(ux*uz+uy*uw); \
            Rt[3]=ts*(ux*uy+uz*uw); Rt[4]=1.0f-ts*(ux*ux+uz*uz); Rt[5]=ts*(uy*uz-ux*uw); \
            Rt[6]=ts*(ux*uz-uy*uw); Rt[7]=ts*(uy*uz+ux*uw); Rt[8]=1.0f-ts*(ux*ux+uy*uy); \
        } \
        float tx = 2.0f * (-vw*ux + vxx*uw - vyy*uz + vzz*uy); \
        float ty = 2.0f * (-vw*uy + vxx*uz + vyy*uw - vzz*ux); \
        float tz = 2.0f * (-vw*uz - vxx*uy + vyy*ux + vzz*uw); \
        float mu0 = Rt[0]*gx_ + Rt[1]*gy_ + Rt[2]*gz_ + tx; \
        float mu1 = Rt[3]*gx_ + Rt[4]*gy_ + Rt[5]*gz_ + ty; \
        float mu2 = Rt[6]*gx_ + Rt[7]*gy_ + Rt[8]*gz_ + tz; \
        long long frb = (long long)N * 3 + (n_) * 9; \
        if (doit_) { \
            if (h == 0) { \
                out[(n_)*3+0] = mu0; out[(n_)*3+1] = mu1; out[(n_)*3+2] = mu2; \
                out[frb+0] = Rt[0]*m0_ + Rt[1]*m3_ + Rt[2]*m6_; \
                out[frb+1] = Rt[0]*m1_ + Rt[1]*m4_ + Rt[2]*m7_; \
                out[frb+2] = Rt[0]*m2_ + Rt[1]*m5_ + Rt[2]*m8_; \
            } else { \
                out[frb+3] = Rt[3]*m0_ + Rt[4]*m3_ + Rt[5]*m6_; \
                out[frb+4] = Rt[3]*m1_ + Rt[4]*m4_ + Rt[5]*m7_; \
                out[frb+5] = Rt[3]*m2_ + Rt[4]*m5_ + Rt[5]*m8_; \
                out[frb+6] = Rt[6]*m0_ + Rt[7]*m3_ + Rt[8]*m6_; \
                out[frb+7] = Rt[6]*m1_ + Rt[7]*m4_ + Rt[8]*m7_; \
                out[frb+8] = Rt[6]*m2_ + Rt[7]*m5_ + Rt[8]*m8_; \
            } \
        } \
    } while (0)

    // point 1 (math overlaps point-2 loads still in flight)
    POINT_BODY(qiA0,qiA1,qiA2,qiA3, qjA0,qjA1,qjA2,qjA3, sA0,sA1,sA2, dA0,dA1,dA2,
               wvA, oA, gAx,gAy,gAz, mA0,mA1,mA2,mA3,mA4,mA5,mA6,mA7,mA8, n1, true);
    // point 2
    POINT_BODY(qiB0,qiB1,qiB2,qiB3, qjB0,qjB1,qjB2,qjB3, sB0,sB1,sB2, dB0,dB1,dB2,
               wvB, oB, gBx,gBy,gBz, mB0,mB1,mB2,mB3,mB4,mB5,mB6,mB7,mB8, n2, v2);

    #undef POINT_BODY
}

extern "C" void kernel_launch(void* const* d_in, const int* in_sizes, int n_in,
                              void* d_out, int out_size, void* d_ws, size_t ws_size,
                              hipStream_t stream) {
    const float* sk_w    = (const float*)d_in[0];
    const float* src_xyz = (const float*)d_in[1];
    const float* s_xyz   = (const float*)d_in[2];
    const float* s_quat  = (const float*)d_in[3];
    const float* d_xyz   = (const float*)d_in[4];
    const float* d_quat  = (const float*)d_in[5];
    const float* dyn_o   = (const float*)d_in[6];
    const float* src_R   = (const float*)d_in[7];
    int N = in_sizes[6];   // dyn_o is [N]
    float* out = (float*)d_out;

    long long half = ((long long)N + 1) >> 1;
    long long threads = half * 2;
    int blocks = (int)((threads + 255) / 256);
    hipLaunchKernelGGL(dqskin_kernel, dim3(blocks), dim3(256), 0, stream,
                       sk_w, src_xyz, s_xyz, s_quat, d_xyz, d_quat, dyn_o, src_R, out, N);
}